// Round 10
// baseline (800.860 us; speedup 1.0000x reference)
//
#include <hip/hip_runtime.h>

typedef unsigned short u16;
typedef unsigned int u32;
typedef __bf16 bf16x8 __attribute__((ext_vector_type(8)));
typedef float f32x4 __attribute__((ext_vector_type(4)));
typedef u16 u16x4 __attribute__((ext_vector_type(4)));

#define NV0 100000
#define NV1 50000
#define NV2 25000
#define NV3 12500

// workspace offsets (in u16 elements)
enum : long {
  OFF_WB0  = 0,
  OFF_WD1  = 27648,
  OFF_WB1  = 44032,
  OFF_WD2  = 154624,
  OFF_WB2  = 220160,
  OFF_WD3  = 662528,
  OFF_WB3  = 924672,
  OFF_WU2  = 2694144,
  OFF_WU1  = 2792448,
  OFF_WU0  = 2833408,
  OFF_WOUT = 2848768,
  OFF_TA   = 2897920,               // scratch x0a/x1a/x2a/x3a; later aliased by f32 tmp
  OFF_X0   = OFF_TA  + 3200000,
  OFF_X1   = OFF_X0  + 3200000,
  OFF_X2   = OFF_X1  + 3200000,
  OFF_X3   = OFF_X2  + 3200000,
  OFF_U2   = OFF_X3  + 3200000,     // also: split-K partial 0 (f32, 12.8MB)
  OFF_U1   = OFF_U2  + 6400000,     // also: split-K partial 1 (f32, 12.8MB)
  OFF_U0S  = OFF_U1  + 6400000,     // 8192*96 bf16
  OFF_END  = OFF_U0S + 786432,
};

__device__ __forceinline__ float b2f(u16 u) {
  union { u32 i; float f; } x; x.i = ((u32)u) << 16; return x.f;
}
__device__ __forceinline__ u16 f2b(float f) {
  union { float f; u32 i; } x; x.f = f;
  u32 r = (x.i + 0x7FFFu + ((x.i >> 16) & 1u)) >> 16;
  return (u16)r;
}
__device__ __forceinline__ void gload16(const u16* g, const u16* l) {
  __builtin_amdgcn_global_load_lds(
      (const __attribute__((address_space(1))) void*)g,
      (__attribute__((address_space(3))) void*)(u16*)l, 16, 0, 0);
}
__device__ __forceinline__ void store_out(u16* p, float v)  { *p = f2b(v); }
__device__ __forceinline__ void store_out(float* p, float v) { *p = v; }
constexpr int ilog2c(int x) { return x <= 1 ? 0 : 1 + ilog2c(x / 2); }

// ---------------- weight transpose prep: f32 W[k][c][o] -> bf16 Wt[k][o][c] ----------------
struct PD { const float* src; u16* dst; int KK, CIN, COUT; };
struct PrepArgs { PD d[11]; };

__global__ __launch_bounds__(256) void prep_k(PrepArgs pa) {
  const PD d = pa.d[blockIdx.y];
  const int cc = d.CIN * d.COUT;
  const int total = d.KK * cc;
  for (int e = blockIdx.x * 256 + threadIdx.x; e < total; e += gridDim.x * 256) {
    int k = e / cc;
    int r = e - k * cc;
    int c = r / d.COUT;
    int o = r - c * d.COUT;
    d.dst[(k * d.COUT + o) * d.CIN + c] = f2b(d.src[e]);
  }
}

// ---------------- stem: f32 [N0,3] gather-conv -> bf16 [N0,32], relu ----------------
__global__ __launch_bounds__(256) void stem_k(const float* __restrict__ feats,
                                              const int* __restrict__ nbr0,
                                              const float* __restrict__ wstem,
                                              u16* __restrict__ out) {
  __shared__ float Wl[27 * 3 * 32];
  const int tid = threadIdx.x;
  for (int i = tid; i < 2592; i += 256) Wl[i] = wstem[i];
  __syncthreads();
  const int n = blockIdx.x * 8 + (tid >> 5);
  const int o = tid & 31;
  if (n >= NV0) return;
  float acc = 0.f;
  const int* nb = nbr0 + n * 27;
  #pragma unroll
  for (int k = 0; k < 27; k++) {
    const int iv = nb[k];
    const float* f = feats + iv * 3;
    acc = fmaf(f[0], Wl[(k * 3 + 0) * 32 + o], acc);
    acc = fmaf(f[1], Wl[(k * 3 + 1) * 32 + o], acc);
    acc = fmaf(f[2], Wl[(k * 3 + 2) * 32 + o], acc);
  }
  out[n * 32 + o] = f2b(fmaxf(acc, 0.f));
}

// ---------------- generic MFMA gather-GEMM ----------------------------------------------
// A: gathered, staged to LDS (global_load_lds, RSH XOR-swizzle, double-buffered,
//    1-barrier pipeline) — the r4/r9-proven structure.
// B: weights (small, L2-hot) loaded DIRECT from global into a loop-carried register
//    set — B(it+1) is issued AFTER the MFMA cluster of iter it, i.e. BEFORE the next
//    barrier, so the barrier's vmcnt(0) drain (needed for the A prefetch anyway)
//    guarantees B has landed at zero added wait.  This fixes r8's mistake (B loaded
//    post-barrier put ~250cy L2 latency on every iteration's critical path).
//    LDS halves: b-layers 39.9KB -> 23.3KB, residency cap 4 -> 7 blocks/CU.
// SWZ=1: XCD sibling co-location (NCB column-blocks of one (row-block,z) on same XCD).
// MODE 0: sparse conv gather  MODE 1: upsample concat  MODE 2: seed concat  MODE 3: plain
// KSPL>1 only for high K*Cout layers (b2/b3) — r7: partial traffic swamps b0/b1.
// Proven-bad: 3-stage counted-vmcnt (r2), BM=32 (r3), BK=32 on big layers (r5/r6),
// B-direct loaded post-barrier (r8), split-K on low-intensity layers (r7).
template <int BM, int BN, int WM, int WN, int COUTF, int KCT, int BK, int MODE,
          int CIN, int KK, int CA, int KSPL, int NCB, int SWZ,
          bool RES, bool DORELU, typename OT>
__global__ __launch_bounds__(256, 6) void gemm_k(
    const u16* __restrict__ src0, const u16* __restrict__ src1,
    const int* __restrict__ idx0, const int* __restrict__ idx1,
    const u16* __restrict__ wt, const u16* __restrict__ base,
    OT* __restrict__ out, int N) {
  constexpr int NWM = BM / WM, NWN = BN / WN;
  static_assert(NWM * NWN == 4, "4 waves");
  constexpr int MI = WM / 16, NI = WN / 16;
  constexpr int CB = KCT - CA;
  constexpr int SLOTS = BK / 8;          // 16B slots per LDS row
  constexpr int SM = SLOTS - 1;
  constexpr int LSL = ilog2c(SLOTS);
  constexpr int RSH = (LSL >= 3) ? 0 : (3 - LSL);  // swizzle row shift (bank coverage)
  constexpr int RPC = 64 / SLOTS;        // rows per 1KB staging chunk
  constexpr int LRPC = ilog2c(RPC);
  constexpr int ACH = (BM * BK) / 512;   // A chunks
  constexpr int NIT = KCT / BK / KSPL;   // iters per split
  constexpr int LOGC = ilog2c(CIN);
  constexpr int ATRIPS = ACH / 4;        // A trips per wave
  constexpr int KKI = BK / 32;           // 32-wide K slices per iter
  constexpr int NIDX = (MODE == 0) ? BM * KK : (MODE == 3 ? 1 : 2 * BM);
  static_assert(ACH % 4 == 0, "A chunks divisible by wave count");
  static_assert(KCT % (BK * KSPL) == 0, "K mult of BK*KSPL");
  static_assert((MODE != 1 && MODE != 2) || (CA % BK == 0), "concat boundary aligned");
  static_assert(KSPL == 1 || MODE == 0, "split only for sparse conv");
  static_assert(MODE != 0 || CIN >= 32, "B 32-slice within one k");

  __shared__ u16 As[2][BM * BK];
  __shared__ int Is[NIDX];
  const int tid = threadIdx.x;
  const int w = tid >> 6, lane = tid & 63;
  const int quad = lane >> 4, l16 = lane & 15;
  const int wm = w % NWM, wn = w / NWM;

  // ---- block coordinates (optionally XCD-sibling-swizzled) ----
  int row0, col0, kbz;
  if constexpr (SWZ) {
    const int NBR = (N + BM - 1) / BM;   // row-blocks
    const int R = NBR * KSPL;            // (row-block, z) pairs
    const int wg = blockIdx.x;
    const int xc = wg & 7, j = wg >> 3;
    const int cb = j % NCB, t = j / NCB;
    const int rt = t * 8 + xc;           // same-XCD blocks walk cb fastest
    if (rt >= R) return;                 // pad block (whole block, pre-barrier)
    row0 = (rt / KSPL) * BM;
    kbz  = rt % KSPL;
    col0 = cb * BN;
  } else {
    row0 = blockIdx.x * BM;
    col0 = blockIdx.y * BN;
    kbz  = blockIdx.z;
  }
  const int Nm1 = N - 1;
  // staging lane geometry (swizzled column group)
  const int srow = lane >> LSL;                    // row within chunk
  const int g    = (lane & SM) ^ ((srow >> RSH) & SM);  // 16B group (logical col/8)
  const int cl   = g * 8;                          // col offset within BK

  // ---- preload PREMULTIPLIED per-row gather offsets into LDS ----
  if constexpr (MODE == 0) {
    for (int e = tid; e < BM * KK; e += 256) {
      const int r = e / KK, k = e - r * KK;
      int n = row0 + r; n = (n > Nm1) ? Nm1 : n;
      Is[e] = idx0[(long)n * KK + k] * CIN;
    }
  } else if constexpr (MODE == 1) {
    for (int e = tid; e < BM; e += 256) {
      int n = row0 + e; n = (n > Nm1) ? Nm1 : n;
      Is[e] = idx0[n] * CA;
      Is[BM + e] = n * CB;
    }
  } else if constexpr (MODE == 2) {
    for (int e = tid; e < BM; e += 256) {
      int n = row0 + e; n = (n > Nm1) ? Nm1 : n;
      const int s = idx0[n];
      Is[e] = idx1[s] * CA;
      Is[BM + e] = s * CB;
    }
  }
  if constexpr (MODE != 3) __syncthreads();

  // ---- per-trip loop-invariant A address components ----
  int pre[ATRIPS];
  #pragma unroll
  for (int t = 0; t < ATRIPS; t++) {
    const int c = w + 4 * t;
    const int r = (c << LRPC) + srow;              // local row, < BM
    if constexpr (MODE == 0) {
      pre[t] = (r * KK + (cl >> LOGC)) * 4;        // byte index into Is (incl per-lane k part)
    } else if constexpr (MODE == 3) {
      int n = row0 + r; n = (n > Nm1) ? Nm1 : n;
      pre[t] = n * KCT + cl;
    } else {
      pre[t] = r * 4;                              // byte index of IsA[r] (IsB at +BM*4)
    }
  }
  const int claneA = (MODE == 0) ? (cl & (CIN - 1)) : cl;

  // ---- B fragment lane-invariant offsets (direct-from-L2 B operand, r8-verified) ----
  int bo[NI];
  #pragma unroll
  for (int j = 0; j < NI; j++) {
    const int o = col0 + wn * WN + j * 16 + l16;
    if constexpr (MODE == 0) bo[j] = o * CIN + quad * 8;   // wt[k][o][c]
    else                     bo[j] = o * KCT + quad * 8;   // wt[o][kc]
  }

  f32x4 acc[MI][NI];
  #pragma unroll
  for (int i = 0; i < MI; i++)
    #pragma unroll
    for (int j = 0; j < NI; j++) acc[i][j] = {0.f, 0.f, 0.f, 0.f};

  auto stage = [&](int buf, int kc0) {             // A-only staging
    int kadd = 0, cadd = 0;
    const u16* sA = src0;
    if constexpr (MODE == 0) {
      kadd = (kc0 >> LOGC) * 4;                    // Is byte advance for current k
      cadd = kc0 & (CIN - 1);                      // in-channel base
    } else if constexpr (MODE == 1 || MODE == 2) {
      if (kc0 >= CA) { kadd = BM * 4; cadd = kc0 - CA; sA = src1; }
      else           { cadd = kc0; }
    }
    #pragma unroll
    for (int t = 0; t < ATRIPS; t++) {
      const int c = w + 4 * t;
      int off;
      if constexpr (MODE == 3) off = pre[t] + kc0;
      else off = *(const int*)((const char*)Is + (pre[t] + kadd)) + cadd + claneA;
      gload16(sA + off, &As[buf][c * 512]);
    }
  };

  // loop-carried B register fragments for the CURRENT iteration
  bf16x8 bB[KKI][NI];
  auto loadB = [&](int kc0) {
    #pragma unroll
    for (int kk = 0; kk < KKI; kk++) {
      const int kc = kc0 + kk * 32;
      int ksc;
      if constexpr (MODE == 0) ksc = (kc >> LOGC) * (COUTF * CIN) + (kc & (CIN - 1));
      else                     ksc = kc;
      #pragma unroll
      for (int j = 0; j < NI; j++)
        bB[kk][j] = *(const bf16x8*)(wt + ksc + bo[j]);
    }
  };

  const int kb = (KSPL > 1) ? kbz * (KCT / KSPL) : 0;
  stage(0, kb);
  loadB(kb);
  #pragma unroll 1
  for (int it = 0; it < NIT; it++) {
    __syncthreads();                     // drains A(it) prefetch AND bB(it) loads
    if (it + 1 < NIT) stage((it + 1) & 1, kb + (it + 1) * BK);  // async A prefetch
    const int buf = it & 1;
    #pragma unroll
    for (int kk = 0; kk < KKI; kk++) {
      bf16x8 af[MI];
      #pragma unroll
      for (int i = 0; i < MI; i++) {
        const int row = wm * WM + i * 16 + l16;
        const int slot = row * SLOTS + (((kk << 2) + quad) ^ ((row >> RSH) & SM));
        af[i] = *(const bf16x8*)&As[buf][slot * 8];
      }
      #pragma unroll
      for (int i = 0; i < MI; i++)
        #pragma unroll
        for (int j = 0; j < NI; j++)
          acc[i][j] = __builtin_amdgcn_mfma_f32_16x16x32_bf16(af[i], bB[kk][j], acc[i][j], 0, 0, 0);
    }
    if (it + 1 < NIT) loadB(kb + (it + 1) * BK);   // B for next iter, issued pre-barrier
  }

  // ---- epilogue: C/D layout col=lane&15, row=quad*4+reg ----
  OT* op = out;
  if constexpr (KSPL > 1) op += (long)kbz * ((long)N * COUTF);
  #pragma unroll
  for (int i = 0; i < MI; i++) {
    #pragma unroll
    for (int j = 0; j < NI; j++) {
      const int col = col0 + wn * WN + j * 16 + l16;
      #pragma unroll
      for (int r = 0; r < 4; r++) {
        const int n = row0 + wm * WM + i * 16 + quad * 4 + r;
        if (n < N) {
          float v = acc[i][j][r];
          if constexpr (RES)         v = b2f(base[(long)n * COUTF + col]) + fmaxf(v, 0.f);
          else if constexpr (DORELU) v = fmaxf(v, 0.f);
          store_out(&op[(long)n * COUTF + col], v);
        }
      }
    }
  }
}

// ---------------- split-K reduce: out = base + relu(p0 + p1), bf16 ----------------
// total elems must be a multiple of 1024 (grid = total/1024, 4 elems/thread)
__global__ __launch_bounds__(256) void fix_k(const float* __restrict__ p0,
                                             const float* __restrict__ p1,
                                             const u16* __restrict__ base,
                                             u16* __restrict__ out) {
  const long i = ((long)blockIdx.x * 256 + threadIdx.x) * 4;
  const f32x4 a = *(const f32x4*)(p0 + i);
  const f32x4 b = *(const f32x4*)(p1 + i);
  const u16x4 bs = *(const u16x4*)(base + i);
  u16x4 r;
  #pragma unroll
  for (int j = 0; j < 4; j++) r[j] = f2b(b2f(bs[j]) + fmaxf(a[j] + b[j], 0.f));
  *(u16x4*)(out + i) = r;
}

// ---------------- final transpose f32 tmp[8192][512] -> f32 out[8][512][1024] ----------------
__global__ __launch_bounds__(256) void tout_k(const float* __restrict__ tmp,
                                              float* __restrict__ outp) {
  __shared__ float tl[64][65];
  const int tid = threadIdx.x;
  const int r0 = blockIdx.x * 64, o0 = blockIdx.y * 64;
  {
    const int rl = tid >> 2, oc = (tid & 3) * 16;
    const float* src = &tmp[(r0 + rl) * 512 + o0 + oc];
    #pragma unroll
    for (int j = 0; j < 16; j++) tl[rl][oc + j] = src[j];
  }
  __syncthreads();
  {
    const int ol = tid >> 2, sc = (tid & 3) * 16;
    const int b = r0 >> 10, s0 = r0 & 1023;
    float* dst = &outp[((long)b * 512 + (o0 + ol)) * 1024 + s0 + sc];
    #pragma unroll
    for (int j = 0; j < 16; j++) dst[j] = tl[sc + j][ol];
  }
}

// host-side: swizzled 1D grid size = ceil(NBR*KSPL/8)*8 * NCB
static inline int swz_grid(int N, int BM, int KSPL, int NCB) {
  const int nbr = (N + BM - 1) / BM;
  const int rp = ((nbr * KSPL + 7) / 8) * 8;
  return rp * NCB;
}

extern "C" void kernel_launch(void* const* d_in, const int* in_sizes, int n_in,
                              void* d_out, int out_size, void* d_ws, size_t ws_size,
                              hipStream_t stream) {
  const float* feats = (const float*)d_in[0];
  const int* nbr0  = (const int*)d_in[1];
  const int* nbr1  = (const int*)d_in[2];
  const int* nbr2  = (const int*)d_in[3];
  const int* nbr3  = (const int*)d_in[4];
  const int* down1 = (const int*)d_in[5];
  const int* down2 = (const int*)d_in[6];
  const int* down3 = (const int*)d_in[7];
  const int* up2   = (const int*)d_in[8];
  const int* up1   = (const int*)d_in[9];
  const int* up0   = (const int*)d_in[10];
  const int* seed  = (const int*)d_in[11];
  u16* ws = (u16*)d_ws;

  PrepArgs pa;
  pa.d[0]  = {(const float*)d_in[13], ws + OFF_WB0,  27, 32, 32};
  pa.d[1]  = {(const float*)d_in[14], ws + OFF_WD1,  8,  32, 64};
  pa.d[2]  = {(const float*)d_in[15], ws + OFF_WB1,  27, 64, 64};
  pa.d[3]  = {(const float*)d_in[16], ws + OFF_WD2,  8,  64, 128};
  pa.d[4]  = {(const float*)d_in[17], ws + OFF_WB2,  27, 128, 128};
  pa.d[5]  = {(const float*)d_in[18], ws + OFF_WD3,  8,  128, 256};
  pa.d[6]  = {(const float*)d_in[19], ws + OFF_WB3,  27, 256, 256};
  pa.d[7]  = {(const float*)d_in[20], ws + OFF_WU2,  1,  384, 256};
  pa.d[8]  = {(const float*)d_in[21], ws + OFF_WU1,  1,  320, 128};
  pa.d[9]  = {(const float*)d_in[22], ws + OFF_WU0,  1,  160, 96};
  pa.d[10] = {(const float*)d_in[23], ws + OFF_WOUT, 1,  96,  512};
  prep_k<<<dim3(128, 11), 256, 0, stream>>>(pa);

  u16* ta  = ws + OFF_TA;
  u16* x0  = ws + OFF_X0;
  u16* x1  = ws + OFF_X1;
  u16* x2  = ws + OFF_X2;
  u16* x3  = ws + OFF_X3;
  u16* u2b = ws + OFF_U2;
  u16* u1b = ws + OFF_U1;
  u16* u0s = ws + OFF_U0S;
  float* tmp  = (float*)(ws + OFF_TA);  // aliases TA/X0/X1 (dead by the time s2 runs)
  float* part = (float*)(ws + OFF_U2);  // split-K partials (2 x 3.2M f32 = U2+U1 regions)

  stem_k<<<12500, 256, 0, stream>>>(feats, nbr0, (const float*)d_in[12], ta);

  // b0: x0 = x0a + relu(conv(x0a, nbr0, W_b0))     [100000 x 32], K=864
  gemm_k<128, 32, 32, 32, 32, 864, 32, 0, 32, 27, 0, 1, 1, 1, true, true, u16>
      <<<swz_grid(NV0, 128, 1, 1), 256, 0, stream>>>(ta, nullptr, nbr0, nullptr, ws + OFF_WB0, ta, x0, NV0);
  // d1: x1a = relu(conv(x0, down1, W_d1))          [50000 x 64], K=256
  gemm_k<64, 64, 32, 32, 64, 256, 64, 0, 32, 8, 0, 1, 1, 1, false, true, u16>
      <<<swz_grid(NV1, 64, 1, 1), 256, 0, stream>>>(x0, nullptr, down1, nullptr, ws + OFF_WD1, nullptr, ta, NV1);
  // b1: x1 = x1a + relu(conv(x1a, nbr1, W_b1))     [50000 x 64], K=1728
  gemm_k<64, 64, 32, 32, 64, 1728, 64, 0, 64, 27, 0, 1, 1, 1, true, true, u16>
      <<<swz_grid(NV1, 64, 1, 1), 256, 0, stream>>>(ta, nullptr, nbr1, nullptr, ws + OFF_WB1, ta, x1, NV1);
  // d2                                             [25000 x 128], K=512, 2 col-blocks co-located
  gemm_k<64, 64, 32, 32, 128, 512, 64, 0, 64, 8, 0, 1, 2, 1, false, true, u16>
      <<<swz_grid(NV2, 64, 1, 2), 256, 0, stream>>>(x1, nullptr, down2, nullptr, ws + OFF_WD2, nullptr, ta, NV2);
  // b2 split-K=2 -> f32 partials, fix: x2 = x2a + relu(p0+p1)   [25000 x 128], K=3456
  gemm_k<64, 64, 32, 32, 128, 3456, 64, 0, 128, 27, 0, 2, 2, 1, false, false, float>
      <<<swz_grid(NV2, 64, 2, 2), 256, 0, stream>>>(ta, nullptr, nbr2, nullptr, ws + OFF_WB2, nullptr, part, NV2);
  fix_k<<<dim3(3125), 256, 0, stream>>>(part, part + 3200000, ta, x2);
  // d3                                             [12500 x 256], K=1024, 4 col-blocks co-located
  gemm_k<64, 64, 32, 32, 256, 1024, 64, 0, 128, 8, 0, 1, 4, 1, false, true, u16>
      <<<swz_grid(NV3, 64, 1, 4), 256, 0, stream>>>(x2, nullptr, down3, nullptr, ws + OFF_WD3, nullptr, ta, NV3);
  // b3 split-K=2 -> f32 partials, fix: x3 = x3a + relu(p0+p1)   [12500 x 256], K=6912
  gemm_k<64, 64, 32, 32, 256, 6912, 64, 0, 256, 27, 0, 2, 4, 1, false, false, float>
      <<<swz_grid(NV3, 64, 2, 4), 256, 0, stream>>>(ta, nullptr, nbr3, nullptr, ws + OFF_WB3, nullptr, part, NV3);
  fix_k<<<dim3(3125), 256, 0, stream>>>(part, part + 3200000, ta, x3);
  // u2 = relu(cat(x3[up2], x2) @ W_u2)             [25000 x 256], K=384
  gemm_k<64, 64, 32, 32, 256, 384, 64, 1, 32, 1, 256, 1, 4, 1, false, true, u16>
      <<<swz_grid(NV2, 64, 1, 4), 256, 0, stream>>>(x3, x2, up2, nullptr, ws + OFF_WU2, nullptr, u2b, NV2);
  // u1 = relu(cat(u2[up1], x1) @ W_u1)             [50000 x 128], K=320
  gemm_k<64, 64, 32, 32, 128, 320, 64, 1, 32, 1, 256, 1, 2, 1, false, true, u16>
      <<<swz_grid(NV1, 64, 1, 2), 256, 0, stream>>>(u2b, x1, up1, nullptr, ws + OFF_WU1, nullptr, u1b, NV1);
  // s1: per-seed u0 = relu(cat(u1[up0[seed]], x0[seed]) @ W_u0)  [8192 x 96], K=160
  gemm_k<64, 96, 32, 48, 96, 160, 32, 2, 32, 1, 128, 1, 1, 0, false, true, u16>
      <<<dim3(128, 1), 256, 0, stream>>>(u1b, x0, seed, up0, ws + OFF_WU0, nullptr, u0s, 8192);
  // s2: tmp = u0s @ W_out                          [8192 x 512] f32, K=96
  gemm_k<64, 64, 32, 32, 512, 96, 32, 3, 32, 1, 0, 1, 1, 0, false, false, float>
      <<<dim3(128, 8), 256, 0, stream>>>(u0s, nullptr, nullptr, nullptr, ws + OFF_WOUT, nullptr, tmp, 8192);
  // transpose to [B, 512, S] f32
  tout_k<<<dim3(128, 8), 256, 0, stream>>>(tmp, (float*)d_out);
}

// Round 11
// 487.145 us; speedup vs baseline: 1.6440x; 1.6440x over previous
//
#include <hip/hip_runtime.h>

typedef unsigned short u16;
typedef unsigned int u32;
typedef __bf16 bf16x8 __attribute__((ext_vector_type(8)));
typedef float f32x4 __attribute__((ext_vector_type(4)));
typedef u16 u16x4 __attribute__((ext_vector_type(4)));

#define NV0 100000
#define NV1 50000
#define NV2 25000
#define NV3 12500

// workspace offsets (in u16 elements)
enum : long {
  OFF_WB0  = 0,
  OFF_WD1  = 27648,
  OFF_WB1  = 44032,
  OFF_WD2  = 154624,
  OFF_WB2  = 220160,
  OFF_WD3  = 662528,
  OFF_WB3  = 924672,
  OFF_WU2  = 2694144,
  OFF_WU1  = 2792448,
  OFF_WU0  = 2833408,
  OFF_WOUT = 2848768,
  OFF_TA   = 2897920,               // scratch x0a/x1a/x2a/x3a; later aliased by f32 tmp
  OFF_X0   = OFF_TA  + 3200000,
  OFF_X1   = OFF_X0  + 3200000,
  OFF_X2   = OFF_X1  + 3200000,
  OFF_X3   = OFF_X2  + 3200000,
  OFF_U2   = OFF_X3  + 3200000,     // also: split-K partial 0 (f32, 12.8MB)
  OFF_U1   = OFF_U2  + 6400000,     // also: split-K partial 1 (f32, 12.8MB)
  OFF_U0S  = OFF_U1  + 6400000,     // 8192*96 bf16
  OFF_END  = OFF_U0S + 786432,
};

__device__ __forceinline__ float b2f(u16 u) {
  union { u32 i; float f; } x; x.i = ((u32)u) << 16; return x.f;
}
__device__ __forceinline__ u16 f2b(float f) {
  union { float f; u32 i; } x; x.f = f;
  u32 r = (x.i + 0x7FFFu + ((x.i >> 16) & 1u)) >> 16;
  return (u16)r;
}
__device__ __forceinline__ void gload16(const u16* g, const u16* l) {
  __builtin_amdgcn_global_load_lds(
      (const __attribute__((address_space(1))) void*)g,
      (__attribute__((address_space(3))) void*)(u16*)l, 16, 0, 0);
}
__device__ __forceinline__ void store_out(u16* p, float v)  { *p = f2b(v); }
__device__ __forceinline__ void store_out(float* p, float v) { *p = v; }
constexpr int ilog2c(int x) { return x <= 1 ? 0 : 1 + ilog2c(x / 2); }

// ---------------- weight transpose prep: f32 W[k][c][o] -> bf16 Wt[k][o][c] ----------------
struct PD { const float* src; u16* dst; int KK, CIN, COUT; };
struct PrepArgs { PD d[11]; };

__global__ __launch_bounds__(256) void prep_k(PrepArgs pa) {
  const PD d = pa.d[blockIdx.y];
  const int cc = d.CIN * d.COUT;
  const int total = d.KK * cc;
  for (int e = blockIdx.x * 256 + threadIdx.x; e < total; e += gridDim.x * 256) {
    int k = e / cc;
    int r = e - k * cc;
    int c = r / d.COUT;
    int o = r - c * d.COUT;
    d.dst[(k * d.COUT + o) * d.CIN + c] = f2b(d.src[e]);
  }
}

// ---------------- stem: f32 [N0,3] gather-conv -> bf16 [N0,32], relu ----------------
__global__ __launch_bounds__(256) void stem_k(const float* __restrict__ feats,
                                              const int* __restrict__ nbr0,
                                              const float* __restrict__ wstem,
                                              u16* __restrict__ out) {
  __shared__ float Wl[27 * 3 * 32];
  const int tid = threadIdx.x;
  for (int i = tid; i < 2592; i += 256) Wl[i] = wstem[i];
  __syncthreads();
  const int n = blockIdx.x * 8 + (tid >> 5);
  const int o = tid & 31;
  if (n >= NV0) return;
  float acc = 0.f;
  const int* nb = nbr0 + n * 27;
  #pragma unroll
  for (int k = 0; k < 27; k++) {
    const int iv = nb[k];
    const float* f = feats + iv * 3;
    acc = fmaf(f[0], Wl[(k * 3 + 0) * 32 + o], acc);
    acc = fmaf(f[1], Wl[(k * 3 + 1) * 32 + o], acc);
    acc = fmaf(f[2], Wl[(k * 3 + 2) * 32 + o], acc);
  }
  out[n * 32 + o] = f2b(fmaxf(acc, 0.f));
}

// ---------------- generic MFMA gather-GEMM, dbuf + 1-barrier pipeline + swizzled LDS ----
// FINAL (r9) structure — best measured 488.1us.  BK=64 big layers, 2-buffer,
// __syncthreads pipeline, RSH swizzle swz(r) = (r >> (3-LSL)) & SM:
//   BK=64: r&7;  BK=32: (r>>1)&3 — both verified 0 bank conflicts.
// SWZ=1: XCD sibling co-location (NCB column-blocks of one (row-block,z) on same XCD).
// MODE 0: sparse conv gather  MODE 1: upsample concat  MODE 2: seed concat  MODE 3: plain
// KSPL>1 only for high K*Cout layers (b2/b3) — r7: partial traffic swamps b0/b1.
// Proven-bad (sessions r2-r10, do not revisit): 3-stage counted-vmcnt (r2), BM=32 (r3),
// BK=32 on big layers (r5/r6), split-K on low-intensity layers (r7), B-direct-from-L2
// in any placement (r8 post-barrier, r10 pre-barrier — compiler sinks the loads to
// their uses, exposing full L2 latency at the barrier drain; VGPR_Count=36 is the tell).
// Remaining limiter: random-gather 16B-request service throughput (TA/L2 fabric) —
// requests are the compulsory unique gather bytes; occupancy 32->50% never helped.
template <int BM, int BN, int WM, int WN, int COUTF, int KCT, int BK, int MODE,
          int CIN, int KK, int CA, int KSPL, int NCB, int SWZ,
          bool RES, bool DORELU, typename OT>
__global__ __launch_bounds__(256, 4) void gemm_k(
    const u16* __restrict__ src0, const u16* __restrict__ src1,
    const int* __restrict__ idx0, const int* __restrict__ idx1,
    const u16* __restrict__ wt, const u16* __restrict__ base,
    OT* __restrict__ out, int N) {
  constexpr int NWM = BM / WM, NWN = BN / WN;
  static_assert(NWM * NWN == 4, "4 waves");
  constexpr int MI = WM / 16, NI = WN / 16;
  constexpr int CB = KCT - CA;
  constexpr int SLOTS = BK / 8;          // 16B slots per LDS row
  constexpr int SM = SLOTS - 1;
  constexpr int LSL = ilog2c(SLOTS);
  constexpr int RSH = (LSL >= 3) ? 0 : (3 - LSL);  // swizzle row shift (bank coverage)
  constexpr int RPC = 64 / SLOTS;        // rows per 1KB staging chunk
  constexpr int LRPC = ilog2c(RPC);
  constexpr int ACH = (BM * BK) / 512;   // A chunks
  constexpr int BCH = (BN * BK) / 512;
  constexpr int NIT = KCT / BK / KSPL;   // iters per split
  constexpr int LOGC = ilog2c(CIN);
  constexpr int ATRIPS = ACH / 4;        // A trips per wave
  constexpr int CTRIPS = (ACH + BCH + 3) / 4;
  constexpr int NIDX = (MODE == 0) ? BM * KK : (MODE == 3 ? 1 : 2 * BM);
  static_assert(ACH % 4 == 0, "A chunks divisible by wave count");
  static_assert(KCT % (BK * KSPL) == 0, "K mult of BK*KSPL");
  static_assert((MODE != 1 && MODE != 2) || (CA % BK == 0), "concat boundary aligned");
  static_assert(KSPL == 1 || MODE == 0, "split only for sparse conv");

  __shared__ u16 As[2][BM * BK];
  __shared__ u16 Bs[2][BN * BK];
  __shared__ int Is[NIDX];
  const int tid = threadIdx.x;
  const int w = tid >> 6, lane = tid & 63;
  const int quad = lane >> 4, l16 = lane & 15;
  const int wm = w % NWM, wn = w / NWM;

  // ---- block coordinates (optionally XCD-sibling-swizzled) ----
  int row0, col0, kbz;
  if constexpr (SWZ) {
    const int NBR = (N + BM - 1) / BM;   // row-blocks
    const int R = NBR * KSPL;            // (row-block, z) pairs
    const int wg = blockIdx.x;
    const int xc = wg & 7, j = wg >> 3;
    const int cb = j % NCB, t = j / NCB;
    const int rt = t * 8 + xc;           // same-XCD blocks walk cb fastest
    if (rt >= R) return;                 // pad block (whole block, pre-barrier)
    row0 = (rt / KSPL) * BM;
    kbz  = rt % KSPL;
    col0 = cb * BN;
  } else {
    row0 = blockIdx.x * BM;
    col0 = blockIdx.y * BN;
    kbz  = blockIdx.z;
  }
  const int Nm1 = N - 1;
  // staging lane geometry (swizzled column group)
  const int srow = lane >> LSL;                    // row within chunk
  const int g    = (lane & SM) ^ ((srow >> RSH) & SM);  // 16B group (logical col/8)
  const int cl   = g * 8;                          // col offset within BK

  // ---- preload PREMULTIPLIED per-row gather offsets into LDS ----
  if constexpr (MODE == 0) {
    for (int e = tid; e < BM * KK; e += 256) {
      const int r = e / KK, k = e - r * KK;
      int n = row0 + r; n = (n > Nm1) ? Nm1 : n;
      Is[e] = idx0[(long)n * KK + k] * CIN;
    }
  } else if constexpr (MODE == 1) {
    for (int e = tid; e < BM; e += 256) {
      int n = row0 + e; n = (n > Nm1) ? Nm1 : n;
      Is[e] = idx0[n] * CA;
      Is[BM + e] = n * CB;
    }
  } else if constexpr (MODE == 2) {
    for (int e = tid; e < BM; e += 256) {
      int n = row0 + e; n = (n > Nm1) ? Nm1 : n;
      const int s = idx0[n];
      Is[e] = idx1[s] * CA;
      Is[BM + e] = s * CB;
    }
  }
  if constexpr (MODE != 3) __syncthreads();

  // ---- per-trip loop-invariant address components (static-indexed regs) ----
  int pre[CTRIPS];
  #pragma unroll
  for (int t = 0; t < CTRIPS; t++) {
    const int c = w + 4 * t;
    if (t < ATRIPS) {
      const int r = (c << LRPC) + srow;            // local row, < BM
      if constexpr (MODE == 0) {
        pre[t] = (r * KK + (cl >> LOGC)) * 4;      // byte index into Is (incl per-lane k part)
      } else if constexpr (MODE == 3) {
        int n = row0 + r; n = (n > Nm1) ? Nm1 : n;
        pre[t] = n * KCT + cl;
      } else {
        pre[t] = r * 4;                            // byte index of IsA[r] (IsB at +BM*4)
      }
    } else if (c < ACH + BCH) {
      const int o = col0 + ((c - ACH) << LRPC) + srow;
      if constexpr (MODE == 0)
        pre[t] = (cl >> LOGC) * (COUTF * CIN) + o * CIN + (cl & (CIN - 1));
      else
        pre[t] = o * KCT + cl;
    }
  }
  const int claneA = (MODE == 0) ? (cl & (CIN - 1)) : cl;

  f32x4 acc[MI][NI];
  #pragma unroll
  for (int i = 0; i < MI; i++)
    #pragma unroll
    for (int j = 0; j < NI; j++) acc[i][j] = {0.f, 0.f, 0.f, 0.f};

  auto stage = [&](int buf, int kc0) {
    // per-iter uniform components (scalar-friendly, computed once)
    int kadd = 0, cadd = 0, kcc = 0;
    const u16* sA = src0;
    if constexpr (MODE == 0) {
      kadd = (kc0 >> LOGC) * 4;                    // Is byte advance for current k
      cadd = kc0 & (CIN - 1);                      // in-channel base
      kcc  = (kc0 >> LOGC) * (COUTF * CIN) + cadd; // weight advance
    } else if constexpr (MODE == 1 || MODE == 2) {
      if (kc0 >= CA) { kadd = BM * 4; cadd = kc0 - CA; sA = src1; }
      else           { cadd = kc0; }
    }
    #pragma unroll
    for (int t = 0; t < CTRIPS; t++) {
      const int c = w + 4 * t;
      if constexpr (CTRIPS * 4 > ACH + BCH) { if (c >= ACH + BCH) continue; }
      if (t < ATRIPS) {
        int off;
        if constexpr (MODE == 3) off = pre[t] + kc0;
        else off = *(const int*)((const char*)Is + (pre[t] + kadd)) + cadd + claneA;
        gload16(sA + off, &As[buf][c * 512]);
      } else {
        int off;
        if constexpr (MODE == 0) off = pre[t] + kcc;
        else                     off = pre[t] + kc0;
        gload16(wt + off, &Bs[buf][(c - ACH) * 512]);
      }
    }
  };

  const int kb = (KSPL > 1) ? kbz * (KCT / KSPL) : 0;
  stage(0, kb);
  #pragma unroll 1
  for (int it = 0; it < NIT; it++) {
    __syncthreads();                     // drains staging of buf it&1 (all waves)
    if (it + 1 < NIT) stage((it + 1) & 1, kb + (it + 1) * BK);  // async prefetch
    const int buf = it & 1;
    #pragma unroll
    for (int kk = 0; kk < BK / 32; kk++) {
      bf16x8 af[MI], bfr[NI];
      #pragma unroll
      for (int i = 0; i < MI; i++) {
        const int row = wm * WM + i * 16 + l16;
        const int slot = row * SLOTS + (((kk << 2) + quad) ^ ((row >> RSH) & SM));
        af[i] = *(const bf16x8*)&As[buf][slot * 8];
      }
      #pragma unroll
      for (int j = 0; j < NI; j++) {
        const int row = wn * WN + j * 16 + l16;
        const int slot = row * SLOTS + (((kk << 2) + quad) ^ ((row >> RSH) & SM));
        bfr[j] = *(const bf16x8*)&Bs[buf][slot * 8];
      }
      #pragma unroll
      for (int i = 0; i < MI; i++)
        #pragma unroll
        for (int j = 0; j < NI; j++)
          acc[i][j] = __builtin_amdgcn_mfma_f32_16x16x32_bf16(af[i], bfr[j], acc[i][j], 0, 0, 0);
    }
  }

  // ---- epilogue: C/D layout col=lane&15, row=quad*4+reg ----
  OT* op = out;
  if constexpr (KSPL > 1) op += (long)kbz * ((long)N * COUTF);
  #pragma unroll
  for (int i = 0; i < MI; i++) {
    #pragma unroll
    for (int j = 0; j < NI; j++) {
      const int col = col0 + wn * WN + j * 16 + l16;
      #pragma unroll
      for (int r = 0; r < 4; r++) {
        const int n = row0 + wm * WM + i * 16 + quad * 4 + r;
        if (n < N) {
          float v = acc[i][j][r];
          if constexpr (RES)         v = b2f(base[(long)n * COUTF + col]) + fmaxf(v, 0.f);
          else if constexpr (DORELU) v = fmaxf(v, 0.f);
          store_out(&op[(long)n * COUTF + col], v);
        }
      }
    }
  }
}

// ---------------- split-K reduce: out = base + relu(p0 + p1), bf16 ----------------
// total elems must be a multiple of 1024 (grid = total/1024, 4 elems/thread)
__global__ __launch_bounds__(256) void fix_k(const float* __restrict__ p0,
                                             const float* __restrict__ p1,
                                             const u16* __restrict__ base,
                                             u16* __restrict__ out) {
  const long i = ((long)blockIdx.x * 256 + threadIdx.x) * 4;
  const f32x4 a = *(const f32x4*)(p0 + i);
  const f32x4 b = *(const f32x4*)(p1 + i);
  const u16x4 bs = *(const u16x4*)(base + i);
  u16x4 r;
  #pragma unroll
  for (int j = 0; j < 4; j++) r[j] = f2b(b2f(bs[j]) + fmaxf(a[j] + b[j], 0.f));
  *(u16x4*)(out + i) = r;
}

// ---------------- final transpose f32 tmp[8192][512] -> f32 out[8][512][1024] ----------------
__global__ __launch_bounds__(256) void tout_k(const float* __restrict__ tmp,
                                              float* __restrict__ outp) {
  __shared__ float tl[64][65];
  const int tid = threadIdx.x;
  const int r0 = blockIdx.x * 64, o0 = blockIdx.y * 64;
  {
    const int rl = tid >> 2, oc = (tid & 3) * 16;
    const float* src = &tmp[(r0 + rl) * 512 + o0 + oc];
    #pragma unroll
    for (int j = 0; j < 16; j++) tl[rl][oc + j] = src[j];
  }
  __syncthreads();
  {
    const int ol = tid >> 2, sc = (tid & 3) * 16;
    const int b = r0 >> 10, s0 = r0 & 1023;
    float* dst = &outp[((long)b * 512 + (o0 + ol)) * 1024 + s0 + sc];
    #pragma unroll
    for (int j = 0; j < 16; j++) dst[j] = tl[sc + j][ol];
  }
}

// host-side: swizzled 1D grid size = ceil(NBR*KSPL/8)*8 * NCB
static inline int swz_grid(int N, int BM, int KSPL, int NCB) {
  const int nbr = (N + BM - 1) / BM;
  const int rp = ((nbr * KSPL + 7) / 8) * 8;
  return rp * NCB;
}

extern "C" void kernel_launch(void* const* d_in, const int* in_sizes, int n_in,
                              void* d_out, int out_size, void* d_ws, size_t ws_size,
                              hipStream_t stream) {
  const float* feats = (const float*)d_in[0];
  const int* nbr0  = (const int*)d_in[1];
  const int* nbr1  = (const int*)d_in[2];
  const int* nbr2  = (const int*)d_in[3];
  const int* nbr3  = (const int*)d_in[4];
  const int* down1 = (const int*)d_in[5];
  const int* down2 = (const int*)d_in[6];
  const int* down3 = (const int*)d_in[7];
  const int* up2   = (const int*)d_in[8];
  const int* up1   = (const int*)d_in[9];
  const int* up0   = (const int*)d_in[10];
  const int* seed  = (const int*)d_in[11];
  u16* ws = (u16*)d_ws;

  PrepArgs pa;
  pa.d[0]  = {(const float*)d_in[13], ws + OFF_WB0,  27, 32, 32};
  pa.d[1]  = {(const float*)d_in[14], ws + OFF_WD1,  8,  32, 64};
  pa.d[2]  = {(const float*)d_in[15], ws + OFF_WB1,  27, 64, 64};
  pa.d[3]  = {(const float*)d_in[16], ws + OFF_WD2,  8,  64, 128};
  pa.d[4]  = {(const float*)d_in[17], ws + OFF_WB2,  27, 128, 128};
  pa.d[5]  = {(const float*)d_in[18], ws + OFF_WD3,  8,  128, 256};
  pa.d[6]  = {(const float*)d_in[19], ws + OFF_WB3,  27, 256, 256};
  pa.d[7]  = {(const float*)d_in[20], ws + OFF_WU2,  1,  384, 256};
  pa.d[8]  = {(const float*)d_in[21], ws + OFF_WU1,  1,  320, 128};
  pa.d[9]  = {(const float*)d_in[22], ws + OFF_WU0,  1,  160, 96};
  pa.d[10] = {(const float*)d_in[23], ws + OFF_WOUT, 1,  96,  512};
  prep_k<<<dim3(128, 11), 256, 0, stream>>>(pa);

  u16* ta  = ws + OFF_TA;
  u16* x0  = ws + OFF_X0;
  u16* x1  = ws + OFF_X1;
  u16* x2  = ws + OFF_X2;
  u16* x3  = ws + OFF_X3;
  u16* u2b = ws + OFF_U2;
  u16* u1b = ws + OFF_U1;
  u16* u0s = ws + OFF_U0S;
  float* tmp  = (float*)(ws + OFF_TA);  // aliases TA/X0/X1 (dead by the time s2 runs)
  float* part = (float*)(ws + OFF_U2);  // split-K partials (2 x 3.2M f32 = U2+U1 regions)

  stem_k<<<12500, 256, 0, stream>>>(feats, nbr0, (const float*)d_in[12], ta);

  // b0: x0 = x0a + relu(conv(x0a, nbr0, W_b0))     [100000 x 32], K=864 (BK=32, RSH-fixed)
  gemm_k<128, 32, 32, 32, 32, 864, 32, 0, 32, 27, 0, 1, 1, 1, true, true, u16>
      <<<swz_grid(NV0, 128, 1, 1), 256, 0, stream>>>(ta, nullptr, nbr0, nullptr, ws + OFF_WB0, ta, x0, NV0);
  // d1: x1a = relu(conv(x0, down1, W_d1))          [50000 x 64], K=256
  gemm_k<64, 64, 32, 32, 64, 256, 64, 0, 32, 8, 0, 1, 1, 1, false, true, u16>
      <<<swz_grid(NV1, 64, 1, 1), 256, 0, stream>>>(x0, nullptr, down1, nullptr, ws + OFF_WD1, nullptr, ta, NV1);
  // b1: x1 = x1a + relu(conv(x1a, nbr1, W_b1))     [50000 x 64], K=1728
  gemm_k<64, 64, 32, 32, 64, 1728, 64, 0, 64, 27, 0, 1, 1, 1, true, true, u16>
      <<<swz_grid(NV1, 64, 1, 1), 256, 0, stream>>>(ta, nullptr, nbr1, nullptr, ws + OFF_WB1, ta, x1, NV1);
  // d2                                             [25000 x 128], K=512, 2 col-blocks co-located
  gemm_k<64, 64, 32, 32, 128, 512, 64, 0, 64, 8, 0, 1, 2, 1, false, true, u16>
      <<<swz_grid(NV2, 64, 1, 2), 256, 0, stream>>>(x1, nullptr, down2, nullptr, ws + OFF_WD2, nullptr, ta, NV2);
  // b2 split-K=2 -> f32 partials, fix: x2 = x2a + relu(p0+p1)   [25000 x 128], K=3456
  gemm_k<64, 64, 32, 32, 128, 3456, 64, 0, 128, 27, 0, 2, 2, 1, false, false, float>
      <<<swz_grid(NV2, 64, 2, 2), 256, 0, stream>>>(ta, nullptr, nbr2, nullptr, ws + OFF_WB2, nullptr, part, NV2);
  fix_k<<<dim3(3125), 256, 0, stream>>>(part, part + 3200000, ta, x2);
  // d3                                             [12500 x 256], K=1024, 4 col-blocks co-located
  gemm_k<64, 64, 32, 32, 256, 1024, 64, 0, 128, 8, 0, 1, 4, 1, false, true, u16>
      <<<swz_grid(NV3, 64, 1, 4), 256, 0, stream>>>(x2, nullptr, down3, nullptr, ws + OFF_WD3, nullptr, ta, NV3);
  // b3 split-K=2 -> f32 partials, fix: x3 = x3a + relu(p0+p1)   [12500 x 256], K=6912
  gemm_k<64, 64, 32, 32, 256, 6912, 64, 0, 256, 27, 0, 2, 4, 1, false, false, float>
      <<<swz_grid(NV3, 64, 2, 4), 256, 0, stream>>>(ta, nullptr, nbr3, nullptr, ws + OFF_WB3, nullptr, part, NV3);
  fix_k<<<dim3(3125), 256, 0, stream>>>(part, part + 3200000, ta, x3);
  // u2 = relu(cat(x3[up2], x2) @ W_u2)             [25000 x 256], K=384
  gemm_k<64, 64, 32, 32, 256, 384, 64, 1, 32, 1, 256, 1, 4, 1, false, true, u16>
      <<<swz_grid(NV2, 64, 1, 4), 256, 0, stream>>>(x3, x2, up2, nullptr, ws + OFF_WU2, nullptr, u2b, NV2);
  // u1 = relu(cat(u2[up1], x1) @ W_u1)             [50000 x 128], K=320
  gemm_k<64, 64, 32, 32, 128, 320, 64, 1, 32, 1, 256, 1, 2, 1, false, true, u16>
      <<<swz_grid(NV1, 64, 1, 2), 256, 0, stream>>>(u2b, x1, up1, nullptr, ws + OFF_WU1, nullptr, u1b, NV1);
  // s1: per-seed u0 = relu(cat(u1[up0[seed]], x0[seed]) @ W_u0)  [8192 x 96], K=160 (RSH-fixed)
  gemm_k<64, 96, 32, 48, 96, 160, 32, 2, 32, 1, 128, 1, 1, 0, false, true, u16>
      <<<dim3(128, 1), 256, 0, stream>>>(u1b, x0, seed, up0, ws + OFF_WU0, nullptr, u0s, 8192);
  // s2: tmp = u0s @ W_out                          [8192 x 512] f32, K=96 (RSH-fixed)
  gemm_k<64, 64, 32, 32, 512, 96, 32, 3, 32, 1, 0, 1, 1, 0, false, false, float>
      <<<dim3(128, 8), 256, 0, stream>>>(u0s, nullptr, nullptr, nullptr, ws + OFF_WOUT, nullptr, tmp, 8192);
  // transpose to [B, 512, S] f32
  tout_k<<<dim3(128, 8), 256, 0, stream>>>(tmp, (float*)d_out);
}